// Round 21
// baseline (48.634 us; speedup 1.0000x reference)
//
#include <hip/hip_runtime.h>

// Fredkin6Layer, algebraically reduced to 9 coefs/gate:
//   a = x[b, (3g+1..3g+3) & 4095],  w = softmax(wgts[g])
//   o0 = (w0+w1)a0 + (w2+w3)a1 + (w4+w5)a2
//   o1 = (w3+w5)a0 + (w1+w4)a1 + (w0+w2)a2
//        + (w0-w1+w2-w3)a0a1 + (w1-w0+w4-w5)a0a2 + (w3-w2+w5-w4)a1a2
//   o2 = (a0+a1+a2) - o0 - o1
//
// R18 form (coalesced gate->thread mapping, scalar stores, depth-3
// register prefetch) at 1 BLOCK/CU: grid 256, NIT=32 rows/block.
// Completes the concurrency sweep (8->4->2 blocks/CU improved every
// matched test; knee never found). Longer streams also halve the
// prologue/tail ratio. R20 proved bytes are at the floor and not the
// limiter (WRITE exactly ideal yet slower) — issue/contention is.

constexpr int DIN  = 4096;
constexpr int NG   = 2048;
constexpr int DOUT = 3 * NG;   // 6144
constexpr int GPB  = 1024;     // gates per block tile
constexpr int NRB  = 128;      // row-tile blocks per gate half
constexpr int RPT  = 4;        // consecutive rows per tile
constexpr int NIT  = 32;       // rows per block (8 tiles)
constexpr int ROWSTEP = RPT * NRB;   // 512

typedef float f4u __attribute__((ext_vector_type(4), aligned(4)));

__global__ __launch_bounds__(256, 1) void fredkin_kernel(
    const float* __restrict__ x,
    const float* __restrict__ wgts,
    float* __restrict__ out)
{
    const int tid = threadIdx.x;
    const int wv  = tid >> 6;
    const int l   = tid & 63;
    const int gt  = blockIdx.x >> 7;         // gate half; pair (b, b+128) ->
    const int rb  = blockIdx.x & (NRB - 1);  //   same XCD (128 % 8 == 0)
    const int g0  = gt * GPB;
    const int base = 3 * g0;                 // 0 or 3072
    const int row0 = rb * RPT;

    // per-u input column (constant across rows) + seam adjust:
    // col == 4093 is the only window whose f4 load would cross the row end.
    int col[4], adj[4];
    #pragma unroll
    for (int u = 0; u < 4; ++u) {
        int c = (base + 768 * wv + 192 * u + 3 * l + 1) & (DIN - 1);
        adj[u] = (c == 4093) ? 1 : 0;
        col[u] = c - adj[u];
    }
    const int obase = base + 768 * wv + 3 * l;   // output word, + 192u per u

    // ---- prefetch rows 0,1,2 (depth 3) before the exp-heavy coef math ----
    f4u buf[4][4];
    {
        const float* xr0 = x + (size_t)row0 * DIN;
        #pragma unroll
        for (int u = 0; u < 4; ++u) {
            buf[0][u] = *(const f4u*)(xr0 + col[u]);
            buf[1][u] = *(const f4u*)(xr0 + DIN + col[u]);
            buf[2][u] = *(const f4u*)(xr0 + 2 * DIN + col[u]);
        }
    }

    // ---- coefficients for the 4 owned gates: g = g0 + 256wv + 64u + l ----
    float cw[4][3], dl_[4][3], qc[4][3];
    #pragma unroll
    for (int u = 0; u < 4; ++u) {
        const int g = g0 + 256 * wv + 64 * u + l;
        const float2* wp = reinterpret_cast<const float2*>(wgts + 6 * g);
        float2 p0 = wp[0], p1 = wp[1], p2 = wp[2];
        float ww0 = p0.x, ww1 = p0.y, ww2 = p1.x,
              ww3 = p1.y, ww4 = p2.x, ww5 = p2.y;
        float m = fmaxf(fmaxf(fmaxf(ww0, ww1), fmaxf(ww2, ww3)),
                        fmaxf(ww4, ww5));
        float e0 = __expf(ww0 - m), e1 = __expf(ww1 - m),
              e2 = __expf(ww2 - m), e3 = __expf(ww3 - m),
              e4 = __expf(ww4 - m), e5 = __expf(ww5 - m);
        float inv = 1.0f / (e0 + e1 + e2 + e3 + e4 + e5);
        e0 *= inv; e1 *= inv; e2 *= inv; e3 *= inv; e4 *= inv; e5 *= inv;
        cw[u][0]  = e0 + e1; cw[u][1]  = e2 + e3; cw[u][2]  = e4 + e5;
        dl_[u][0] = e3 + e5; dl_[u][1] = e1 + e4; dl_[u][2] = e0 + e2;
        qc[u][0]  = e0 - e1 + e2 - e3;
        qc[u][1]  = e1 - e0 + e4 - e5;
        qc[u][2]  = e3 - e2 + e5 - e4;
    }

    #pragma unroll
    for (int i = 0; i < NIT; ++i) {
        const int cur = i % 4;
        const int drow = (i >> 2) * ROWSTEP + (i & 3);
        // prefetch row i+3 into the buffer freed three iters ago
        if (i + 3 < NIT) {
            const int nx = (i + 3) % 4;
            const int dn = ((i + 3) >> 2) * ROWSTEP + ((i + 3) & 3);
            const float* xr = x + (size_t)(row0 + dn) * DIN;
            #pragma unroll
            for (int u = 0; u < 4; ++u)
                buf[nx][u] = *(const f4u*)(xr + col[u]);
        }

        const size_t orow = (size_t)(row0 + drow) * DOUT;
        #pragma unroll
        for (int u = 0; u < 4; ++u) {
            f4u v = buf[cur][u];
            // seam lane loaded at col-1: take .yzw instead of .xyz
            float a0 = adj[u] ? v.y : v.x;
            float a1 = adj[u] ? v.z : v.y;
            float a2 = adj[u] ? v.w : v.z;

            float p01 = a0 * a1, p02 = a0 * a2, p12 = a1 * a2;
            float t0 = cw[u][0] * a0 + cw[u][1] * a1 + cw[u][2] * a2;
            float qq = qc[u][0] * p01 + qc[u][1] * p02 + qc[u][2] * p12;
            float t1 = dl_[u][0] * a0 + dl_[u][1] * a1 + dl_[u][2] * a2 + qq;
            float t2 = (a0 + a1 + a2) - t0 - t1;

            // 12B-contiguous per lane; wave covers 768B per u with full
            // line coverage (scalar stores: R20 proved the typed dwordx3
            // form reaches ideal bytes but loses time — keep R18's form).
            float* op = out + (orow + (size_t)(obase + 192 * u));
            op[0] = t0;
            op[1] = t1;
            op[2] = t2;
        }
    }
}

extern "C" void kernel_launch(void* const* d_in, const int* in_sizes, int n_in,
                              void* d_out, int out_size, void* d_ws, size_t ws_size,
                              hipStream_t stream) {
    const float* x    = (const float*)d_in[0];   // (4096, 4096) f32
    const float* wgts = (const float*)d_in[1];   // (2048, 6)   f32
    // d_in[2] = connections — deterministic (3g+1+k) % DIN, not needed.
    float* out = (float*)d_out;                  // (4096, 6144) f32

    const int grid = 2 * NRB;                    // 256 blocks = 1 per CU
    fredkin_kernel<<<grid, 256, 0, stream>>>(x, wgts, out);
}

// Round 22
// 30.982 us; speedup vs baseline: 1.5698x; 1.5698x over previous
//
#include <hip/hip_runtime.h>

// Fredkin6Layer, algebraically reduced to 9 coefs/gate:
//   a = x[b, (3g+1..3g+3) & 4095],  w = softmax(wgts[g])
//   o0 = (w0+w1)a0 + (w2+w3)a1 + (w4+w5)a2
//   o1 = (w3+w5)a0 + (w1+w4)a1 + (w0+w2)a2
//        + (w0-w1+w2-w3)a0a1 + (w1-w0+w4-w5)a0a2 + (w3-w2+w5-w4)a1a2
//   o2 = (a0+a1+a2) - o0 - o1
//
// FINAL: R18 configuration — the measured optimum of the full sweep.
//   mapping:  thread (wv,l) owns gates {256wv+64u+l} -> per u the wave's
//             inputs/outputs are 12B-per-lane CONTIGUOUS (loads: align-4
//             dwordx4; stores: 3 scalar floats, LLVM-merged, full-line
//             coverage). This removed the partial-line packet tax that
//             capped the 48B-stride mapping at 4.3 TB/s (+25%).
//   grid:     512 blocks = 2 blocks/CU — concurrency knee (1/CU=48.6us,
//             2/CU=31.0, 4/CU=34.7, 8/CU=67; L2 write churn above,
//             latency starvation below).
//   pipeline: depth-3 register prefetch, 16 rows/block, no LDS/barriers.
//   rejected: NT stores (bypass L2 write-combining: 2.7x worse), typed
//             dwordx3 (ideal bytes, worse time), LDS transpose, 8/CU.
// Traffic at floor (WRITE exactly 98304 KiB ideal in R20/R21 probes);
// ~5 TB/s effective on this mixed 1:2 read:write stream.

constexpr int DIN  = 4096;
constexpr int NG   = 2048;
constexpr int DOUT = 3 * NG;   // 6144
constexpr int GPB  = 1024;     // gates per block tile
constexpr int NRB  = 256;      // row-tile blocks per gate half
constexpr int RPT  = 4;        // consecutive rows per tile
constexpr int NIT  = 16;       // rows per block
constexpr int ROWSTEP = RPT * NRB;   // 1024

typedef float f4u __attribute__((ext_vector_type(4), aligned(4)));

__global__ __launch_bounds__(256, 2) void fredkin_kernel(
    const float* __restrict__ x,
    const float* __restrict__ wgts,
    float* __restrict__ out)
{
    const int tid = threadIdx.x;
    const int wv  = tid >> 6;
    const int l   = tid & 63;
    const int gt  = blockIdx.x >> 8;         // gate half; pair (b, b+256) ->
    const int rb  = blockIdx.x & (NRB - 1);  //   same XCD (256 % 8 == 0)
    const int g0  = gt * GPB;
    const int base = 3 * g0;                 // 0 or 3072
    const int row0 = rb * RPT;

    // per-u input column (constant across rows) + seam adjust:
    // col == 4093 is the only window whose f4 load would cross the row end.
    int col[4], adj[4];
    #pragma unroll
    for (int u = 0; u < 4; ++u) {
        int c = (base + 768 * wv + 192 * u + 3 * l + 1) & (DIN - 1);
        adj[u] = (c == 4093) ? 1 : 0;
        col[u] = c - adj[u];
    }
    const int obase = base + 768 * wv + 3 * l;   // output word, + 192u per u

    // ---- prefetch rows 0,1,2 (depth 3) before the exp-heavy coef math ----
    f4u buf[4][4];
    {
        const float* xr0 = x + (size_t)row0 * DIN;
        #pragma unroll
        for (int u = 0; u < 4; ++u) {
            buf[0][u] = *(const f4u*)(xr0 + col[u]);
            buf[1][u] = *(const f4u*)(xr0 + DIN + col[u]);
            buf[2][u] = *(const f4u*)(xr0 + 2 * DIN + col[u]);
        }
    }

    // ---- coefficients for the 4 owned gates: g = g0 + 256wv + 64u + l ----
    float cw[4][3], dl_[4][3], qc[4][3];
    #pragma unroll
    for (int u = 0; u < 4; ++u) {
        const int g = g0 + 256 * wv + 64 * u + l;
        const float2* wp = reinterpret_cast<const float2*>(wgts + 6 * g);
        float2 p0 = wp[0], p1 = wp[1], p2 = wp[2];
        float ww0 = p0.x, ww1 = p0.y, ww2 = p1.x,
              ww3 = p1.y, ww4 = p2.x, ww5 = p2.y;
        float m = fmaxf(fmaxf(fmaxf(ww0, ww1), fmaxf(ww2, ww3)),
                        fmaxf(ww4, ww5));
        float e0 = __expf(ww0 - m), e1 = __expf(ww1 - m),
              e2 = __expf(ww2 - m), e3 = __expf(ww3 - m),
              e4 = __expf(ww4 - m), e5 = __expf(ww5 - m);
        float inv = 1.0f / (e0 + e1 + e2 + e3 + e4 + e5);
        e0 *= inv; e1 *= inv; e2 *= inv; e3 *= inv; e4 *= inv; e5 *= inv;
        cw[u][0]  = e0 + e1; cw[u][1]  = e2 + e3; cw[u][2]  = e4 + e5;
        dl_[u][0] = e3 + e5; dl_[u][1] = e1 + e4; dl_[u][2] = e0 + e2;
        qc[u][0]  = e0 - e1 + e2 - e3;
        qc[u][1]  = e1 - e0 + e4 - e5;
        qc[u][2]  = e3 - e2 + e5 - e4;
    }

    #pragma unroll
    for (int i = 0; i < NIT; ++i) {
        const int cur = i % 4;
        const int drow = (i >> 2) * ROWSTEP + (i & 3);
        // prefetch row i+3 into the buffer freed three iters ago
        if (i + 3 < NIT) {
            const int nx = (i + 3) % 4;
            const int dn = ((i + 3) >> 2) * ROWSTEP + ((i + 3) & 3);
            const float* xr = x + (size_t)(row0 + dn) * DIN;
            #pragma unroll
            for (int u = 0; u < 4; ++u)
                buf[nx][u] = *(const f4u*)(xr + col[u]);
        }

        const size_t orow = (size_t)(row0 + drow) * DOUT;
        #pragma unroll
        for (int u = 0; u < 4; ++u) {
            f4u v = buf[cur][u];
            // seam lane loaded at col-1: take .yzw instead of .xyz
            float a0 = adj[u] ? v.y : v.x;
            float a1 = adj[u] ? v.z : v.y;
            float a2 = adj[u] ? v.w : v.z;

            float p01 = a0 * a1, p02 = a0 * a2, p12 = a1 * a2;
            float t0 = cw[u][0] * a0 + cw[u][1] * a1 + cw[u][2] * a2;
            float qq = qc[u][0] * p01 + qc[u][1] * p02 + qc[u][2] * p12;
            float t1 = dl_[u][0] * a0 + dl_[u][1] * a1 + dl_[u][2] * a2 + qq;
            float t2 = (a0 + a1 + a2) - t0 - t1;

            // 12B-contiguous per lane; wave covers 768B per u with full
            // line coverage (merged dwordx3 at align 4).
            float* op = out + (orow + (size_t)(obase + 192 * u));
            op[0] = t0;
            op[1] = t1;
            op[2] = t2;
        }
    }
}

extern "C" void kernel_launch(void* const* d_in, const int* in_sizes, int n_in,
                              void* d_out, int out_size, void* d_ws, size_t ws_size,
                              hipStream_t stream) {
    const float* x    = (const float*)d_in[0];   // (4096, 4096) f32
    const float* wgts = (const float*)d_in[1];   // (2048, 6)   f32
    // d_in[2] = connections — deterministic (3g+1+k) % DIN, not needed.
    float* out = (float*)d_out;                  // (4096, 6144) f32

    const int grid = 2 * NRB;                    // 512 blocks = 2 per CU
    fredkin_kernel<<<grid, 256, 0, stream>>>(x, wgts, out);
}